// Round 6
// baseline (1158.600 us; speedup 1.0000x reference)
//
#include <hip/hip_runtime.h>
#include <hip/hip_bf16.h>

// GCNII fused, bf16 pre-scaled activations (xs = dinv*x), src-only CSR,
// 4-node-slot gather waves, degree-sorted node permutation.
// N=100000, E=1000000, F=64.
// Output: concat(out1 [N*4], out2 [N*3], h [N*64]) fp32.

#define TPB 256
#define WROW 66   // W^T row stride in floats (8B-aligned, bank-rotated)
typedef __hip_bfloat16 bf16;

__device__ __forceinline__ float lo16(int u) { return __int_as_float(u << 16); }
__device__ __forceinline__ float hi16(int u) { return __int_as_float(u & 0xffff0000); }

// ---- degree count ----
__global__ void deg_count_kernel(const int* __restrict__ col, int* __restrict__ degi, int E) {
    int e = blockIdx.x * blockDim.x + threadIdx.x;
    if (e < E) atomicAdd(&degi[col[e]], 1);
}

// dinv = rsqrt(deg+1), sdeg = sqrt(deg+1)
__global__ void dinv_kernel(const int* __restrict__ degi, float* __restrict__ dinv,
                            float* __restrict__ sdeg, int n) {
    int v = blockIdx.x * blockDim.x + threadIdx.x;
    if (v < n) {
        float d = (float)degi[v] + 1.0f;
        dinv[v] = rsqrtf(d);
        sdeg[v] = sqrtf(d);
    }
}

// ---- exclusive scan of degi -> rowptr (3-phase, chunks of 1024) ----
__global__ void scan_block_kernel(const int* __restrict__ degi, int* __restrict__ rowptr,
                                  int* __restrict__ blksum, int n) {
    __shared__ int s[256];
    int base = blockIdx.x * 1024;
    int t = threadIdx.x;
    int v[4]; int sum = 0;
#pragma unroll
    for (int i = 0; i < 4; ++i) {
        int idx = base + t * 4 + i;
        v[i] = (idx < n) ? degi[idx] : 0;
        sum += v[i];
    }
    s[t] = sum;
    __syncthreads();
    for (int off = 1; off < 256; off <<= 1) {
        int val = (t >= off) ? s[t - off] : 0;
        __syncthreads();
        s[t] += val;
        __syncthreads();
    }
    int excl = s[t] - sum;
    if (t == 255) blksum[blockIdx.x] = s[255];
    int run = excl;
#pragma unroll
    for (int i = 0; i < 4; ++i) {
        int idx = base + t * 4 + i;
        if (idx < n) rowptr[idx] = run;
        run += v[i];
    }
}

__global__ void scan_top_kernel(int* __restrict__ blksum, int* __restrict__ blkoff, int nblk) {
    __shared__ int s[256];
    int t = threadIdx.x;
    int mine = (t < nblk) ? blksum[t] : 0;
    s[t] = mine;
    __syncthreads();
    for (int off = 1; off < 256; off <<= 1) {
        int val = (t >= off) ? s[t - off] : 0;
        __syncthreads();
        s[t] += val;
        __syncthreads();
    }
    if (t < nblk) blkoff[t] = s[t] - mine;  // exclusive
}

__global__ void scan_add_kernel(int* __restrict__ rowptr, int* __restrict__ cursor,
                                const int* __restrict__ blkoff, int n) {
    int idx = blockIdx.x * blockDim.x + threadIdx.x;
    if (idx < n) {
        int val = rowptr[idx] + blkoff[idx >> 10];
        rowptr[idx] = val;
        cursor[idx] = val;
    }
}

// ---- scatter edges (src id only, 4B) into dst-sorted buckets ----
__global__ void scatter_kernel(const int* __restrict__ ei, int* __restrict__ cursor,
                               int* __restrict__ srcids, int E) {
    int e = blockIdx.x * blockDim.x + threadIdx.x;
    if (e < E) {
        int r = ei[e];
        int c = ei[E + e];
        int pos = atomicAdd(&cursor[c], 1);
        srcids[pos] = r;
    }
}

// ---- degree histogram / scan / place -> degree-sorted perm ----
__global__ void dhist_kernel(const int* __restrict__ degi, int* __restrict__ dh, int n) {
    int v = blockIdx.x * blockDim.x + threadIdx.x;
    if (v < n) atomicAdd(&dh[min(degi[v], 255)], 1);
}

__global__ void dscan_kernel(const int* __restrict__ dh, int* __restrict__ dcur) {
    __shared__ int s[256];
    int t = threadIdx.x;
    int mine = dh[t];
    s[t] = mine;
    __syncthreads();
    for (int off = 1; off < 256; off <<= 1) {
        int val = (t >= off) ? s[t - off] : 0;
        __syncthreads();
        s[t] += val;
        __syncthreads();
    }
    dcur[t] = s[t] - mine;  // exclusive
}

__global__ void place_kernel(const int* __restrict__ degi, int* __restrict__ dcur,
                             int* __restrict__ perm, int n) {
    int v = blockIdx.x * blockDim.x + threadIdx.x;
    if (v < n) {
        int pos = atomicAdd(&dcur[min(degi[v], 255)], 1);
        perm[pos] = v;
    }
}

// ---- x0s = bf16(dinv[v] * x) ----
__global__ void cvt_kernel(const float* __restrict__ x, const float* __restrict__ dinv,
                           unsigned short* __restrict__ xb, int n4) {
    int i = blockIdx.x * blockDim.x + threadIdx.x;
    if (i < n4) {
        float dv = dinv[i >> 4];
        float4 f = ((const float4*)x)[i];
        bf16 b0 = __float2bfloat16(f.x * dv), b1 = __float2bfloat16(f.y * dv);
        bf16 b2 = __float2bfloat16(f.z * dv), b3 = __float2bfloat16(f.w * dv);
        ushort4 u;
        u.x = *(unsigned short*)&b0; u.y = *(unsigned short*)&b1;
        u.z = *(unsigned short*)&b2; u.w = *(unsigned short*)&b3;
        ((ushort4*)xb)[i] = u;
    }
}

// ---- stage W^T into LDS at row stride WROW: Wsm[j*WROW + k] = W[k*64 + j] ----
__device__ __forceinline__ void stage_w(const float* __restrict__ W, float* __restrict__ Wsm) {
    for (int i = threadIdx.x; i < 4096; i += TPB)
        Wsm[(i & 63) * WROW + (i >> 6)] = W[i];
}

// o[lane] = sum_k t[k] * W[k][lane]; immediate-offset LDS reads.
__device__ __forceinline__ float mm64(const float* __restrict__ Wsm, const float* __restrict__ t,
                                      int lane) {
    const float* wrow = &Wsm[lane * WROW];
    float o = 0.0f;
#pragma unroll
    for (int k4 = 0; k4 < 16; ++k4) {
        float4 tt = *(const float4*)(t + k4 * 4);          // b128 broadcast
        float2 wa = *(const float2*)(wrow + k4 * 4);
        float2 wb = *(const float2*)(wrow + k4 * 4 + 2);
        o = fmaf(tt.x, wa.x, o);
        o = fmaf(tt.y, wa.y, o);
        o = fmaf(tt.z, wb.x, o);
        o = fmaf(tt.w, wb.y, o);
    }
    return o;
}

// ---- 4-slot gather: lane = (slot s = lane>>4, feature-quad g = lane&15) ----
// acc[0..3] = sum over slot's edges of xs[src][4g..4g+3]; masked beyond deg.
struct GRes { float a0, a1, a2, a3; };
__device__ __forceinline__ GRes gather4(const int* __restrict__ srcids, int beg, int deg, int md,
                                        const unsigned short* __restrict__ rowoff) {
    GRes r{0.0f, 0.0f, 0.0f, 0.0f};
    for (int i = 0; i < md; i += 2) {
        int i0 = (i < deg) ? i : 0;
        int i1 = (i + 1 < deg) ? (i + 1) : 0;
        int src0 = srcids[beg + i0];
        int src1 = srcids[beg + i1];
        int2 q0 = *(const int2*)(rowoff + ((size_t)(unsigned)src0 << 6));
        int2 q1 = *(const int2*)(rowoff + ((size_t)(unsigned)src1 << 6));
        float m0 = (i < deg) ? 1.0f : 0.0f;
        float m1 = (i + 1 < deg) ? 1.0f : 0.0f;
        r.a0 = fmaf(m0, lo16(q0.x), r.a0);
        r.a1 = fmaf(m0, hi16(q0.x), r.a1);
        r.a2 = fmaf(m0, lo16(q0.y), r.a2);
        r.a3 = fmaf(m0, hi16(q0.y), r.a3);
        r.a0 = fmaf(m1, lo16(q1.x), r.a0);
        r.a1 = fmaf(m1, hi16(q1.x), r.a1);
        r.a2 = fmaf(m1, lo16(q1.y), r.a2);
        r.a3 = fmaf(m1, hi16(q1.y), r.a3);
    }
    return r;
}

// ---- fused GCN2Conv layer: ys_out = dinv * relu( t @ W ),
//      t = 0.9*dinv*(S + xs_self) + 0.1*sdeg*xs_self ----
__global__ __launch_bounds__(256) void layer_kernel(
        const int* __restrict__ rowptr, const int* __restrict__ degi,
        const int* __restrict__ srcids, const int* __restrict__ perm,
        const unsigned short* __restrict__ xsb, const float* __restrict__ dinv,
        const float* __restrict__ sdeg, const float* __restrict__ W,
        unsigned short* __restrict__ yb, int n) {
    __shared__ __align__(16) float st[4][4][64];
    __shared__ __align__(16) float Wsm[64 * WROW];
    int wid = threadIdx.x >> 6;
    int lane = threadIdx.x & 63;
    int s = lane >> 4;
    int g = lane & 15;
    stage_w(W, Wsm);
    __syncthreads();
    int ntile = (n + 15) >> 4;
    for (int tile = blockIdx.x; tile < ntile; tile += gridDim.x) {
        int base = tile * 16 + wid * 4;
        // ---- phase A: gather + combine, 4 nodes per wave ----
        int vb = base + s;
        int vbc = (vb < n) ? vb : n - 1;
        int v = perm[vbc];
        int beg = rowptr[v];
        int deg = degi[v];
        int md = max(deg, __shfl_xor(deg, 16));
        md = max(md, __shfl_xor(md, 32));
        const unsigned short* rowoff = xsb + (g << 2);
        GRes r = gather4(srcids, beg, deg, md, rowoff);
        int2 qs = *(const int2*)(rowoff + ((size_t)(unsigned)v << 6));
        float xs0 = lo16(qs.x), xs1 = hi16(qs.x), xs2 = lo16(qs.y), xs3 = hi16(qs.y);
        float c9 = 0.9f * dinv[v];
        float c1 = 0.1f * sdeg[v];
        float4 t4;
        t4.x = c9 * (r.a0 + xs0) + c1 * xs0;
        t4.y = c9 * (r.a1 + xs1) + c1 * xs1;
        t4.z = c9 * (r.a2 + xs2) + c1 * xs2;
        t4.w = c9 * (r.a3 + xs3) + c1 * xs3;
        *(float4*)&st[wid][s][g * 4] = t4;
        __builtin_amdgcn_wave_barrier();
        // ---- phase B: matmul, one node at a time (lane = output col) ----
#pragma unroll
        for (int ss = 0; ss < 4; ++ss) {
            int vb2 = base + ss;
            if (vb2 >= n) break;
            int v2 = perm[vb2];
            float o = fmaxf(mm64(Wsm, st[wid][ss], lane), 0.0f);
            bf16 ob = __float2bfloat16(dinv[v2] * o);
            yb[(size_t)(unsigned)v2 * 64 + lane] = *(unsigned short*)&ob;
        }
        __builtin_amdgcn_wave_barrier();
    }
}

// ---- plain matmul: xws = x3s @ W_gcn (scales cancel exactly) ----
__global__ __launch_bounds__(256) void mm_kernel(
        const unsigned short* __restrict__ xb, const float* __restrict__ W,
        unsigned short* __restrict__ yb, int n) {
    __shared__ __align__(16) float st[4][64];
    __shared__ __align__(16) float Wsm[64 * WROW];
    int wid = threadIdx.x >> 6;
    int lane = threadIdx.x & 63;
    stage_w(W, Wsm);
    __syncthreads();
    int stride = gridDim.x * 4;
    for (int v = blockIdx.x * 4 + wid; v < n; v += stride) {
        const unsigned short* selfp = xb + ((size_t)(unsigned)v << 6);
        st[wid][lane] = __int_as_float(((int)selfp[lane]) << 16);
        __builtin_amdgcn_wave_barrier();
        float o = mm64(Wsm, st[wid], lane);
        __builtin_amdgcn_wave_barrier();
        bf16 ob = __float2bfloat16(o);
        yb[(size_t)(unsigned)v * 64 + lane] = *(unsigned short*)&ob;
    }
}

// ---- final: h = dinv*(S + xws_self) + b_gcn; out1 = h@W1+b1; out2 = h@W2+b2 ----
__global__ __launch_bounds__(256) void heads_kernel(
        const int* __restrict__ rowptr, const int* __restrict__ degi,
        const int* __restrict__ srcids, const int* __restrict__ perm,
        const unsigned short* __restrict__ xwb, const float* __restrict__ dinv,
        const float* __restrict__ bg,
        const float* __restrict__ W1, const float* __restrict__ b1,
        const float* __restrict__ W2, const float* __restrict__ b2,
        float* __restrict__ out, int n) {
    __shared__ __align__(16) float hs[4][4][64];
    __shared__ __align__(16) float whd[448];   // whd[j*64+k], j=0..6
    __shared__ float bs[8];
    int wid = threadIdx.x >> 6;
    int lane = threadIdx.x & 63;
    int s = lane >> 4;
    int g = lane & 15;
    for (int i = threadIdx.x; i < 448; i += TPB) {   // blockDim 256 < 448: loop!
        int j = i >> 6, k = i & 63;
        whd[i] = (j < 4) ? W1[k * 4 + j] : W2[k * 3 + (j - 4)];
    }
    if (threadIdx.x < 7) bs[threadIdx.x] = (threadIdx.x < 4) ? b1[threadIdx.x] : b2[threadIdx.x - 4];
    __syncthreads();
    int j = lane >> 3;            // head output index for phase B
    int k0 = (lane & 7) * 8;
    int ntile = (n + 15) >> 4;
    for (int tile = blockIdx.x; tile < ntile; tile += gridDim.x) {
        int base = tile * 16 + wid * 4;
        // ---- phase A ----
        int vb = base + s;
        int vbc = (vb < n) ? vb : n - 1;
        int v = perm[vbc];
        int beg = rowptr[v];
        int deg = degi[v];
        int md = max(deg, __shfl_xor(deg, 16));
        md = max(md, __shfl_xor(md, 32));
        const unsigned short* rowoff = xwb + (g << 2);
        GRes r = gather4(srcids, beg, deg, md, rowoff);
        int2 qs = *(const int2*)(rowoff + ((size_t)(unsigned)v << 6));
        float dv = dinv[v];
        float4 bq = *(const float4*)(bg + g * 4);
        float4 h4;
        h4.x = dv * (r.a0 + lo16(qs.x)) + bq.x;
        h4.y = dv * (r.a1 + hi16(qs.x)) + bq.y;
        h4.z = dv * (r.a2 + lo16(qs.y)) + bq.z;
        h4.w = dv * (r.a3 + hi16(qs.y)) + bq.w;
        if (vb < n)
            *(float4*)&out[(size_t)7 * n + (size_t)(unsigned)v * 64 + g * 4] = h4;
        *(float4*)&hs[wid][s][g * 4] = h4;
        __builtin_amdgcn_wave_barrier();
        // ---- phase B: tiny heads, one node at a time ----
#pragma unroll
        for (int ss = 0; ss < 4; ++ss) {
            int vb2 = base + ss;
            if (vb2 >= n) break;
            int v2 = perm[vb2];
            float part = 0.0f;
            if (j < 7) {
                float4 h0 = *(const float4*)&hs[wid][ss][k0];
                float4 h1 = *(const float4*)&hs[wid][ss][k0 + 4];
                const float4* wq = (const float4*)&whd[j * 64 + k0];
                float4 w0 = wq[0], w1 = wq[1];
                part = h0.x * w0.x + h0.y * w0.y + h0.z * w0.z + h0.w * w0.w
                     + h1.x * w1.x + h1.y * w1.y + h1.z * w1.z + h1.w * w1.w;
            }
            part += __shfl_down(part, 4);
            part += __shfl_down(part, 2);
            part += __shfl_down(part, 1);
            if ((lane & 7) == 0 && j < 7) {
                float sv = bs[j] + part;
                if (j < 4) out[(size_t)v2 * 4 + j] = sv;
                else       out[(size_t)4 * n + (size_t)v2 * 3 + (j - 4)] = sv;
            }
        }
        __builtin_amdgcn_wave_barrier();
    }
}

extern "C" void kernel_launch(void* const* d_in, const int* in_sizes, int n_in,
                              void* d_out, int out_size, void* d_ws, size_t ws_size,
                              hipStream_t stream) {
    const float* x     = (const float*)d_in[0];
    const int*   ei    = (const int*)d_in[1];
    const float* Ws    = (const float*)d_in[2];
    const float* W_gcn = (const float*)d_in[3];
    const float* b_gcn = (const float*)d_in[4];
    const float* W1    = (const float*)d_in[5];
    const float* b1    = (const float*)d_in[6];
    const float* W2    = (const float*)d_in[7];
    const float* b2    = (const float*)d_in[8];
    float* out = (float*)d_out;

    const int N = in_sizes[0] / 64;
    const int E = in_sizes[1] / 2;
    const int NLAYERS = in_sizes[2] / 4096;  // L-1 = 3

    // ws layout (ints): degi[N] rowptr[N] cursor[N] blksum[256] blkoff[256]
    //                   dh[256] dcur[256] perm[N] srcids[E+64]
    // (floats): dinv[N] sdeg[N] | (ushort): x0s, bufA, bufB (N*64 each)
    int*   degi   = (int*)d_ws;
    int*   rowptr = degi + N;
    int*   cursor = rowptr + N;
    int*   blksum = cursor + N;
    int*   blkoff = blksum + 256;
    int*   dh     = blkoff + 256;
    int*   dcur   = dh + 256;
    int*   perm   = dcur + 256;
    int*   srcids = perm + N;
    float* dinv   = (float*)(srcids + E + 64);
    float* sdeg   = dinv + N;
    unsigned short* x0s  = (unsigned short*)(sdeg + N);
    unsigned short* bufA = x0s + (size_t)N * 64;
    unsigned short* bufB = bufA + (size_t)N * 64;

    const int nblk = (N + 1023) / 1024;
    const int grid_e = (E + TPB - 1) / TPB;
    const int grid_n = (N + TPB - 1) / TPB;
    const int WGRID = 4096;

    // ---- CSR build + degree sort ----
    hipMemsetAsync(degi, 0, (size_t)N * sizeof(int), stream);
    hipMemsetAsync(dh, 0, 256 * sizeof(int), stream);
    hipMemsetAsync(srcids + E, 0, 64 * sizeof(int), stream);  // gather tail pad
    deg_count_kernel<<<grid_e, TPB, 0, stream>>>(ei + E, degi, E);
    dinv_kernel<<<grid_n, TPB, 0, stream>>>(degi, dinv, sdeg, N);
    scan_block_kernel<<<nblk, 256, 0, stream>>>(degi, rowptr, blksum, N);
    scan_top_kernel<<<1, 256, 0, stream>>>(blksum, blkoff, nblk);
    scan_add_kernel<<<grid_n, TPB, 0, stream>>>(rowptr, cursor, blkoff, N);
    scatter_kernel<<<grid_e, TPB, 0, stream>>>(ei, cursor, srcids, E);
    dhist_kernel<<<grid_n, TPB, 0, stream>>>(degi, dh, N);
    dscan_kernel<<<1, 256, 0, stream>>>(dh, dcur);
    place_kernel<<<grid_n, TPB, 0, stream>>>(degi, dcur, perm, N);
    cvt_kernel<<<(N * 16 + TPB - 1) / TPB, TPB, 0, stream>>>(x, dinv, x0s, N * 16);

    // ---- GCN2Conv layers ----
    const unsigned short* xcur = x0s;
    unsigned short* ybuf = bufA;
    for (int i = 0; i < NLAYERS; ++i) {
        layer_kernel<<<WGRID, TPB, 0, stream>>>(rowptr, degi, srcids, perm, xcur,
                                                dinv, sdeg, Ws + (size_t)i * 4096, ybuf, N);
        xcur = ybuf;
        ybuf = (ybuf == bufA) ? bufB : bufA;
    }

    // ---- GCNConv + heads ----
    unsigned short* xw = ybuf;
    mm_kernel<<<WGRID, TPB, 0, stream>>>(xcur, W_gcn, xw, N);
    heads_kernel<<<WGRID, TPB, 0, stream>>>(rowptr, degi, srcids, perm, xw, dinv,
                                            b_gcn, W1, b1, W2, b2, out, N);
}

// Round 7
// 507.666 us; speedup vs baseline: 2.2822x; 2.2822x over previous
//
#include <hip/hip_runtime.h>
#include <hip/hip_bf16.h>

// GCNII fused, bf16 pre-scaled activations (xs = dinv*x), src-only CSR,
// 4-node-slot gather waves, degree-sorted node permutation (LDS-privatized sort).
// N=100000, E=1000000, F=64.
// Output: concat(out1 [N*4], out2 [N*3], h [N*64]) fp32.

#define TPB 256
#define WROW 66   // W^T row stride in floats (8B-aligned, bank-rotated)
typedef __hip_bfloat16 bf16;

__device__ __forceinline__ float lo16(int u) { return __int_as_float(u << 16); }
__device__ __forceinline__ float hi16(int u) { return __int_as_float(u & 0xffff0000); }

// ---- degree count ----
__global__ void deg_count_kernel(const int* __restrict__ col, int* __restrict__ degi, int E) {
    int e = blockIdx.x * blockDim.x + threadIdx.x;
    if (e < E) atomicAdd(&degi[col[e]], 1);
}

// dinv = rsqrt(deg+1), sdeg = sqrt(deg+1)
__global__ void dinv_kernel(const int* __restrict__ degi, float* __restrict__ dinv,
                            float* __restrict__ sdeg, int n) {
    int v = blockIdx.x * blockDim.x + threadIdx.x;
    if (v < n) {
        float d = (float)degi[v] + 1.0f;
        dinv[v] = rsqrtf(d);
        sdeg[v] = sqrtf(d);
    }
}

// ---- exclusive scan of degi -> rowptr (3-phase, chunks of 1024) ----
__global__ void scan_block_kernel(const int* __restrict__ degi, int* __restrict__ rowptr,
                                  int* __restrict__ blksum, int n) {
    __shared__ int s[256];
    int base = blockIdx.x * 1024;
    int t = threadIdx.x;
    int v[4]; int sum = 0;
#pragma unroll
    for (int i = 0; i < 4; ++i) {
        int idx = base + t * 4 + i;
        v[i] = (idx < n) ? degi[idx] : 0;
        sum += v[i];
    }
    s[t] = sum;
    __syncthreads();
    for (int off = 1; off < 256; off <<= 1) {
        int val = (t >= off) ? s[t - off] : 0;
        __syncthreads();
        s[t] += val;
        __syncthreads();
    }
    int excl = s[t] - sum;
    if (t == 255) blksum[blockIdx.x] = s[255];
    int run = excl;
#pragma unroll
    for (int i = 0; i < 4; ++i) {
        int idx = base + t * 4 + i;
        if (idx < n) rowptr[idx] = run;
        run += v[i];
    }
}

__global__ void scan_top_kernel(int* __restrict__ blksum, int* __restrict__ blkoff, int nblk) {
    __shared__ int s[256];
    int t = threadIdx.x;
    int mine = (t < nblk) ? blksum[t] : 0;
    s[t] = mine;
    __syncthreads();
    for (int off = 1; off < 256; off <<= 1) {
        int val = (t >= off) ? s[t - off] : 0;
        __syncthreads();
        s[t] += val;
        __syncthreads();
    }
    if (t < nblk) blkoff[t] = s[t] - mine;  // exclusive
}

__global__ void scan_add_kernel(int* __restrict__ rowptr, int* __restrict__ cursor,
                                const int* __restrict__ blkoff, int n) {
    int idx = blockIdx.x * blockDim.x + threadIdx.x;
    if (idx < n) {
        int val = rowptr[idx] + blkoff[idx >> 10];
        rowptr[idx] = val;
        cursor[idx] = val;
    }
}

// ---- scatter edges (src id only, 4B) into dst-sorted buckets ----
__global__ void scatter_kernel(const int* __restrict__ ei, int* __restrict__ cursor,
                               int* __restrict__ srcids, int E) {
    int e = blockIdx.x * blockDim.x + threadIdx.x;
    if (e < E) {
        int r = ei[e];
        int c = ei[E + e];
        int pos = atomicAdd(&cursor[c], 1);
        srcids[pos] = r;
    }
}

// ---- degree histogram, LDS-privatized (round-6 fix: 100k global atomics on
//      256 addresses was 332 us; now 64 blocks x 256 lightly-contended adds) ----
__global__ void dhist_kernel(const int* __restrict__ degi, int* __restrict__ dh, int n) {
    __shared__ int lh[256];
    lh[threadIdx.x] = 0;
    __syncthreads();
    for (int v = blockIdx.x * blockDim.x + threadIdx.x; v < n; v += gridDim.x * blockDim.x)
        atomicAdd(&lh[min(degi[v], 255)], 1);
    __syncthreads();
    int c = lh[threadIdx.x];
    if (c) atomicAdd(&dh[threadIdx.x], c);
}

__global__ void dscan_kernel(const int* __restrict__ dh, int* __restrict__ dcur) {
    __shared__ int s[256];
    int t = threadIdx.x;
    int mine = dh[t];
    s[t] = mine;
    __syncthreads();
    for (int off = 1; off < 256; off <<= 1) {
        int val = (t >= off) ? s[t - off] : 0;
        __syncthreads();
        s[t] += val;
        __syncthreads();
    }
    dcur[t] = s[t] - mine;  // exclusive
}

// ---- placement: per-block chunk, LDS hist -> bulk range reservation -> LDS rank ----
__global__ void place_kernel(const int* __restrict__ degi, int* __restrict__ dcur,
                             int* __restrict__ perm, int n) {
    __shared__ int lh[256], lb[256];
    int chunk = (n + gridDim.x - 1) / gridDim.x;
    int beg = blockIdx.x * chunk;
    int end = min(beg + chunk, n);
    lh[threadIdx.x] = 0;
    __syncthreads();
    for (int v = beg + threadIdx.x; v < end; v += blockDim.x)
        atomicAdd(&lh[min(degi[v], 255)], 1);
    __syncthreads();
    int c = lh[threadIdx.x];
    lb[threadIdx.x] = c ? atomicAdd(&dcur[threadIdx.x], c) : 0;  // one global atomic per bin
    __syncthreads();
    lh[threadIdx.x] = 0;
    __syncthreads();
    for (int v = beg + threadIdx.x; v < end; v += blockDim.x) {
        int bin = min(degi[v], 255);
        int r = atomicAdd(&lh[bin], 1);          // LDS rank
        perm[lb[bin] + r] = v;
    }
}

// ---- x0s = bf16(dinv[v] * x) ----
__global__ void cvt_kernel(const float* __restrict__ x, const float* __restrict__ dinv,
                           unsigned short* __restrict__ xb, int n4) {
    int i = blockIdx.x * blockDim.x + threadIdx.x;
    if (i < n4) {
        float dv = dinv[i >> 4];
        float4 f = ((const float4*)x)[i];
        bf16 b0 = __float2bfloat16(f.x * dv), b1 = __float2bfloat16(f.y * dv);
        bf16 b2 = __float2bfloat16(f.z * dv), b3 = __float2bfloat16(f.w * dv);
        ushort4 u;
        u.x = *(unsigned short*)&b0; u.y = *(unsigned short*)&b1;
        u.z = *(unsigned short*)&b2; u.w = *(unsigned short*)&b3;
        ((ushort4*)xb)[i] = u;
    }
}

// ---- stage W^T into LDS at row stride WROW: Wsm[j*WROW + k] = W[k*64 + j] ----
__device__ __forceinline__ void stage_w(const float* __restrict__ W, float* __restrict__ Wsm) {
    for (int i = threadIdx.x; i < 4096; i += TPB)
        Wsm[(i & 63) * WROW + (i >> 6)] = W[i];
}

// o[lane] = sum_k t[k] * W[k][lane]; immediate-offset LDS reads.
__device__ __forceinline__ float mm64(const float* __restrict__ Wsm, const float* __restrict__ t,
                                      int lane) {
    const float* wrow = &Wsm[lane * WROW];
    float o = 0.0f;
#pragma unroll
    for (int k4 = 0; k4 < 16; ++k4) {
        float4 tt = *(const float4*)(t + k4 * 4);          // b128 broadcast
        float2 wa = *(const float2*)(wrow + k4 * 4);
        float2 wb = *(const float2*)(wrow + k4 * 4 + 2);
        o = fmaf(tt.x, wa.x, o);
        o = fmaf(tt.y, wa.y, o);
        o = fmaf(tt.z, wb.x, o);
        o = fmaf(tt.w, wb.y, o);
    }
    return o;
}

// ---- 4-slot gather: lane = (slot s = lane>>4, feature-quad g = lane&15) ----
struct GRes { float a0, a1, a2, a3; };
__device__ __forceinline__ GRes gather4(const int* __restrict__ srcids, int beg, int deg, int md,
                                        const unsigned short* __restrict__ rowoff) {
    GRes r{0.0f, 0.0f, 0.0f, 0.0f};
    for (int i = 0; i < md; i += 2) {
        int i0 = (i < deg) ? i : 0;
        int i1 = (i + 1 < deg) ? (i + 1) : 0;
        int src0 = srcids[beg + i0];
        int src1 = srcids[beg + i1];
        int2 q0 = *(const int2*)(rowoff + ((size_t)(unsigned)src0 << 6));
        int2 q1 = *(const int2*)(rowoff + ((size_t)(unsigned)src1 << 6));
        float m0 = (i < deg) ? 1.0f : 0.0f;
        float m1 = (i + 1 < deg) ? 1.0f : 0.0f;
        r.a0 = fmaf(m0, lo16(q0.x), r.a0);
        r.a1 = fmaf(m0, hi16(q0.x), r.a1);
        r.a2 = fmaf(m0, lo16(q0.y), r.a2);
        r.a3 = fmaf(m0, hi16(q0.y), r.a3);
        r.a0 = fmaf(m1, lo16(q1.x), r.a0);
        r.a1 = fmaf(m1, hi16(q1.x), r.a1);
        r.a2 = fmaf(m1, lo16(q1.y), r.a2);
        r.a3 = fmaf(m1, hi16(q1.y), r.a3);
    }
    return r;
}

// ---- fused GCN2Conv layer: ys_out = dinv * relu( t @ W ),
//      t = 0.9*dinv*(S + xs_self) + 0.1*sdeg*xs_self ----
__global__ __launch_bounds__(256) void layer_kernel(
        const int* __restrict__ rowptr, const int* __restrict__ degi,
        const int* __restrict__ srcids, const int* __restrict__ perm,
        const unsigned short* __restrict__ xsb, const float* __restrict__ dinv,
        const float* __restrict__ sdeg, const float* __restrict__ W,
        unsigned short* __restrict__ yb, int n) {
    __shared__ __align__(16) float st[4][4][64];
    __shared__ __align__(16) float Wsm[64 * WROW];
    int wid = threadIdx.x >> 6;
    int lane = threadIdx.x & 63;
    int s = lane >> 4;
    int g = lane & 15;
    stage_w(W, Wsm);
    __syncthreads();
    int ntile = (n + 15) >> 4;
    for (int tile = blockIdx.x; tile < ntile; tile += gridDim.x) {
        int base = tile * 16 + wid * 4;
        // ---- phase A: gather + combine, 4 nodes per wave ----
        int vb = base + s;
        int vbc = (vb < n) ? vb : n - 1;
        int v = perm[vbc];
        int beg = rowptr[v];
        int deg = degi[v];
        int md = max(deg, __shfl_xor(deg, 16));
        md = max(md, __shfl_xor(md, 32));
        const unsigned short* rowoff = xsb + (g << 2);
        GRes r = gather4(srcids, beg, deg, md, rowoff);
        int2 qs = *(const int2*)(rowoff + ((size_t)(unsigned)v << 6));
        float xs0 = lo16(qs.x), xs1 = hi16(qs.x), xs2 = lo16(qs.y), xs3 = hi16(qs.y);
        float c9 = 0.9f * dinv[v];
        float c1 = 0.1f * sdeg[v];
        float4 t4;
        t4.x = c9 * (r.a0 + xs0) + c1 * xs0;
        t4.y = c9 * (r.a1 + xs1) + c1 * xs1;
        t4.z = c9 * (r.a2 + xs2) + c1 * xs2;
        t4.w = c9 * (r.a3 + xs3) + c1 * xs3;
        *(float4*)&st[wid][s][g * 4] = t4;
        __builtin_amdgcn_wave_barrier();
        // ---- phase B: matmul, one node at a time (lane = output col) ----
#pragma unroll
        for (int ss = 0; ss < 4; ++ss) {
            int vb2 = base + ss;
            if (vb2 >= n) break;
            int v2 = perm[vb2];
            float o = fmaxf(mm64(Wsm, st[wid][ss], lane), 0.0f);
            bf16 ob = __float2bfloat16(dinv[v2] * o);
            yb[(size_t)(unsigned)v2 * 64 + lane] = *(unsigned short*)&ob;
        }
        __builtin_amdgcn_wave_barrier();
    }
}

// ---- plain matmul: xws = x3s @ W_gcn (scales cancel exactly) ----
__global__ __launch_bounds__(256) void mm_kernel(
        const unsigned short* __restrict__ xb, const float* __restrict__ W,
        unsigned short* __restrict__ yb, int n) {
    __shared__ __align__(16) float st[4][64];
    __shared__ __align__(16) float Wsm[64 * WROW];
    int wid = threadIdx.x >> 6;
    int lane = threadIdx.x & 63;
    stage_w(W, Wsm);
    __syncthreads();
    int stride = gridDim.x * 4;
    for (int v = blockIdx.x * 4 + wid; v < n; v += stride) {
        const unsigned short* selfp = xb + ((size_t)(unsigned)v << 6);
        st[wid][lane] = __int_as_float(((int)selfp[lane]) << 16);
        __builtin_amdgcn_wave_barrier();
        float o = mm64(Wsm, st[wid], lane);
        __builtin_amdgcn_wave_barrier();
        bf16 ob = __float2bfloat16(o);
        yb[(size_t)(unsigned)v * 64 + lane] = *(unsigned short*)&ob;
    }
}

// ---- final: h = dinv*(S + xws_self) + b_gcn; out1 = h@W1+b1; out2 = h@W2+b2 ----
__global__ __launch_bounds__(256) void heads_kernel(
        const int* __restrict__ rowptr, const int* __restrict__ degi,
        const int* __restrict__ srcids, const int* __restrict__ perm,
        const unsigned short* __restrict__ xwb, const float* __restrict__ dinv,
        const float* __restrict__ bg,
        const float* __restrict__ W1, const float* __restrict__ b1,
        const float* __restrict__ W2, const float* __restrict__ b2,
        float* __restrict__ out, int n) {
    __shared__ __align__(16) float hs[4][4][64];
    __shared__ __align__(16) float whd[448];   // whd[j*64+k], j=0..6
    __shared__ float bs[8];
    int wid = threadIdx.x >> 6;
    int lane = threadIdx.x & 63;
    int s = lane >> 4;
    int g = lane & 15;
    for (int i = threadIdx.x; i < 448; i += TPB) {   // blockDim 256 < 448: loop!
        int j = i >> 6, k = i & 63;
        whd[i] = (j < 4) ? W1[k * 4 + j] : W2[k * 3 + (j - 4)];
    }
    if (threadIdx.x < 7) bs[threadIdx.x] = (threadIdx.x < 4) ? b1[threadIdx.x] : b2[threadIdx.x - 4];
    __syncthreads();
    int j = lane >> 3;            // head output index for phase B
    int k0 = (lane & 7) * 8;
    int ntile = (n + 15) >> 4;
    for (int tile = blockIdx.x; tile < ntile; tile += gridDim.x) {
        int base = tile * 16 + wid * 4;
        // ---- phase A ----
        int vb = base + s;
        int vbc = (vb < n) ? vb : n - 1;
        int v = perm[vbc];
        int beg = rowptr[v];
        int deg = degi[v];
        int md = max(deg, __shfl_xor(deg, 16));
        md = max(md, __shfl_xor(md, 32));
        const unsigned short* rowoff = xwb + (g << 2);
        GRes r = gather4(srcids, beg, deg, md, rowoff);
        int2 qs = *(const int2*)(rowoff + ((size_t)(unsigned)v << 6));
        float dv = dinv[v];
        float4 bq = *(const float4*)(bg + g * 4);
        float4 h4;
        h4.x = dv * (r.a0 + lo16(qs.x)) + bq.x;
        h4.y = dv * (r.a1 + hi16(qs.x)) + bq.y;
        h4.z = dv * (r.a2 + lo16(qs.y)) + bq.z;
        h4.w = dv * (r.a3 + hi16(qs.y)) + bq.w;
        if (vb < n)
            *(float4*)&out[(size_t)7 * n + (size_t)(unsigned)v * 64 + g * 4] = h4;
        *(float4*)&hs[wid][s][g * 4] = h4;
        __builtin_amdgcn_wave_barrier();
        // ---- phase B: tiny heads, one node at a time ----
#pragma unroll
        for (int ss = 0; ss < 4; ++ss) {
            int vb2 = base + ss;
            if (vb2 >= n) break;
            int v2 = perm[vb2];
            float part = 0.0f;
            if (j < 7) {
                float4 h0 = *(const float4*)&hs[wid][ss][k0];
                float4 h1 = *(const float4*)&hs[wid][ss][k0 + 4];
                const float4* wq = (const float4*)&whd[j * 64 + k0];
                float4 w0 = wq[0], w1 = wq[1];
                part = h0.x * w0.x + h0.y * w0.y + h0.z * w0.z + h0.w * w0.w
                     + h1.x * w1.x + h1.y * w1.y + h1.z * w1.z + h1.w * w1.w;
            }
            part += __shfl_down(part, 4);
            part += __shfl_down(part, 2);
            part += __shfl_down(part, 1);
            if ((lane & 7) == 0 && j < 7) {
                float sv = bs[j] + part;
                if (j < 4) out[(size_t)v2 * 4 + j] = sv;
                else       out[(size_t)4 * n + (size_t)v2 * 3 + (j - 4)] = sv;
            }
        }
        __builtin_amdgcn_wave_barrier();
    }
}

extern "C" void kernel_launch(void* const* d_in, const int* in_sizes, int n_in,
                              void* d_out, int out_size, void* d_ws, size_t ws_size,
                              hipStream_t stream) {
    const float* x     = (const float*)d_in[0];
    const int*   ei    = (const int*)d_in[1];
    const float* Ws    = (const float*)d_in[2];
    const float* W_gcn = (const float*)d_in[3];
    const float* b_gcn = (const float*)d_in[4];
    const float* W1    = (const float*)d_in[5];
    const float* b1    = (const float*)d_in[6];
    const float* W2    = (const float*)d_in[7];
    const float* b2    = (const float*)d_in[8];
    float* out = (float*)d_out;

    const int N = in_sizes[0] / 64;
    const int E = in_sizes[1] / 2;
    const int NLAYERS = in_sizes[2] / 4096;  // L-1 = 3

    // ws layout (ints): degi[N] rowptr[N] cursor[N] blksum[256] blkoff[256]
    //                   dh[256] dcur[256] perm[N] srcids[E+64]
    // (floats): dinv[N] sdeg[N] | (ushort): x0s, bufA, bufB (N*64 each)
    int*   degi   = (int*)d_ws;
    int*   rowptr = degi + N;
    int*   cursor = rowptr + N;
    int*   blksum = cursor + N;
    int*   blkoff = blksum + 256;
    int*   dh     = blkoff + 256;
    int*   dcur   = dh + 256;
    int*   perm   = dcur + 256;
    int*   srcids = perm + N;
    float* dinv   = (float*)(srcids + E + 64);
    float* sdeg   = dinv + N;
    unsigned short* x0s  = (unsigned short*)(sdeg + N);
    unsigned short* bufA = x0s + (size_t)N * 64;
    unsigned short* bufB = bufA + (size_t)N * 64;

    const int nblk = (N + 1023) / 1024;
    const int grid_e = (E + TPB - 1) / TPB;
    const int grid_n = (N + TPB - 1) / TPB;
    const int WGRID = 4096;

    // ---- CSR build + degree sort ----
    hipMemsetAsync(degi, 0, (size_t)N * sizeof(int), stream);
    hipMemsetAsync(dh, 0, 256 * sizeof(int), stream);
    hipMemsetAsync(srcids + E, 0, 64 * sizeof(int), stream);  // gather tail pad
    deg_count_kernel<<<grid_e, TPB, 0, stream>>>(ei + E, degi, E);
    dinv_kernel<<<grid_n, TPB, 0, stream>>>(degi, dinv, sdeg, N);
    scan_block_kernel<<<nblk, 256, 0, stream>>>(degi, rowptr, blksum, N);
    scan_top_kernel<<<1, 256, 0, stream>>>(blksum, blkoff, nblk);
    scan_add_kernel<<<grid_n, TPB, 0, stream>>>(rowptr, cursor, blkoff, N);
    scatter_kernel<<<grid_e, TPB, 0, stream>>>(ei, cursor, srcids, E);
    dhist_kernel<<<64, 256, 0, stream>>>(degi, dh, N);
    dscan_kernel<<<1, 256, 0, stream>>>(dh, dcur);
    place_kernel<<<64, 256, 0, stream>>>(degi, dcur, perm, N);
    cvt_kernel<<<(N * 16 + TPB - 1) / TPB, TPB, 0, stream>>>(x, dinv, x0s, N * 16);

    // ---- GCN2Conv layers ----
    const unsigned short* xcur = x0s;
    unsigned short* ybuf = bufA;
    for (int i = 0; i < NLAYERS; ++i) {
        layer_kernel<<<WGRID, TPB, 0, stream>>>(rowptr, degi, srcids, perm, xcur,
                                                dinv, sdeg, Ws + (size_t)i * 4096, ybuf, N);
        xcur = ybuf;
        ybuf = (ybuf == bufA) ? bufB : bufA;
    }

    // ---- GCNConv + heads ----
    unsigned short* xw = ybuf;
    mm_kernel<<<WGRID, TPB, 0, stream>>>(xcur, W_gcn, xw, N);
    heads_kernel<<<WGRID, TPB, 0, stream>>>(rowptr, degi, srcids, perm, xw, dinv,
                                            b_gcn, W1, b1, W2, b2, out, N);
}

// Round 8
// 434.245 us; speedup vs baseline: 2.6681x; 1.1691x over previous
//
#include <hip/hip_runtime.h>
#include <hip/hip_bf16.h>

// GCNII fused, bf16 pre-scaled activations (xs = dinv*x), src-only CSR built by
// two-pass bucket sort (no scattered-line writes), 4-node-slot gather waves,
// degree-sorted node permutation. N=100000, E=1000000, F=64.
// Output: concat(out1 [N*4], out2 [N*3], h [N*64]) fp32.
// NOTE: record packing (dst&127)<<17 | src requires N <= 131072.

#define TPB 256
#define WROW 66   // W^T row stride in floats (8B-aligned, bank-rotated)
#define NBSH 7    // 128 nodes per bucket
typedef __hip_bfloat16 bf16;

__device__ __forceinline__ float lo16(int u) { return __int_as_float(u << 16); }
__device__ __forceinline__ float hi16(int u) { return __int_as_float(u & 0xffff0000); }

// ---- pass 0: bucket histogram (LDS-privatized) ----
__global__ void ebhist_kernel(const int* __restrict__ col, int* __restrict__ bh,
                              int E, int B) {
    __shared__ int lh[800];
    for (int i = threadIdx.x; i < B; i += blockDim.x) lh[i] = 0;
    __syncthreads();
    for (int e = blockIdx.x * blockDim.x + threadIdx.x; e < E; e += gridDim.x * blockDim.x)
        atomicAdd(&lh[col[e] >> NBSH], 1);
    __syncthreads();
    for (int i = threadIdx.x; i < B; i += blockDim.x) {
        int c = lh[i];
        if (c) atomicAdd(&bh[i], c);
    }
}

// ---- exclusive scan of bh -> bcur (cursors) and boff (bounds, boff[B]=E) ----
__global__ void bscan_kernel(const int* __restrict__ bh, int* __restrict__ bcur,
                             int* __restrict__ boff, int B, int E) {
    __shared__ int s[256];
    int t = threadIdx.x;
    int v[4]; int sum = 0;
#pragma unroll
    for (int i = 0; i < 4; ++i) {
        int idx = t * 4 + i;
        v[i] = (idx < B) ? bh[idx] : 0;
        sum += v[i];
    }
    s[t] = sum;
    __syncthreads();
    for (int off = 1; off < 256; off <<= 1) {
        int val = (t >= off) ? s[t - off] : 0;
        __syncthreads();
        s[t] += val;
        __syncthreads();
    }
    int run = s[t] - sum;
#pragma unroll
    for (int i = 0; i < 4; ++i) {
        int idx = t * 4 + i;
        if (idx < B) { bcur[idx] = run; boff[idx] = run; }
        run += v[i];
    }
    if (t == 255) boff[B] = E;
}

// ---- pass 1: bucket scatter with per-block range reservation ----
__global__ void bucket_scatter_kernel(const int* __restrict__ ei, int* __restrict__ bcur,
                                      unsigned int* __restrict__ ebuf, int E, int B) {
    __shared__ int lh[800], lb[800];
    int chunk = (E + gridDim.x - 1) / gridDim.x;
    int beg = blockIdx.x * chunk;
    int end = min(beg + chunk, E);
    for (int i = threadIdx.x; i < B; i += blockDim.x) lh[i] = 0;
    __syncthreads();
    for (int e = beg + threadIdx.x; e < end; e += blockDim.x)
        atomicAdd(&lh[ei[E + e] >> NBSH], 1);
    __syncthreads();
    for (int i = threadIdx.x; i < B; i += blockDim.x) {
        int c = lh[i];
        lb[i] = c ? atomicAdd(&bcur[i], c) : 0;   // one global atomic per bin per block
    }
    __syncthreads();
    for (int i = threadIdx.x; i < B; i += blockDim.x) lh[i] = 0;
    __syncthreads();
    for (int e = beg + threadIdx.x; e < end; e += blockDim.x) {
        int r = ei[e];
        int c = ei[E + e];
        int bin = c >> NBSH;
        int rank = atomicAdd(&lh[bin], 1);        // LDS rank
        ebuf[lb[bin] + rank] = ((unsigned)(c & 127) << 17) | (unsigned)r;
    }
}

// ---- pass 2: per-bucket place; also emits degi/rowptr/dinv/sdeg ----
__global__ __launch_bounds__(128) void bucket_place_kernel(
        const int* __restrict__ boff, const unsigned int* __restrict__ ebuf,
        int* __restrict__ rowptr, int* __restrict__ degi,
        float* __restrict__ dinv, float* __restrict__ sdeg,
        int* __restrict__ srcids, int n) {
    __shared__ int cnt[128], loff[128], lcur[128];
    int b = blockIdx.x;
    int t = threadIdx.x;
    int lo = boff[b];
    int hi = boff[b + 1];
    int vbase = b << NBSH;
    cnt[t] = 0;
    __syncthreads();
    for (int i = lo + t; i < hi; i += 128)
        atomicAdd(&cnt[ebuf[i] >> 17], 1);
    __syncthreads();
    int mine = cnt[t];
    loff[t] = mine;
    __syncthreads();
    for (int off = 1; off < 128; off <<= 1) {
        int val = (t >= off) ? loff[t - off] : 0;
        __syncthreads();
        loff[t] += val;
        __syncthreads();
    }
    int excl = loff[t] - mine;
    int v = vbase + t;
    if (v < n) {
        rowptr[v] = lo + excl;
        degi[v] = mine;
        float d = (float)mine + 1.0f;
        dinv[v] = rsqrtf(d);
        sdeg[v] = sqrtf(d);
    }
    lcur[t] = lo + excl;
    __syncthreads();
    for (int i = lo + t; i < hi; i += 128) {
        unsigned int r = ebuf[i];
        int pos = atomicAdd(&lcur[r >> 17], 1);
        srcids[pos] = (int)(r & 0x1FFFFu);
    }
}

// ---- degree histogram (LDS-privatized) ----
__global__ void dhist_kernel(const int* __restrict__ degi, int* __restrict__ dh, int n) {
    __shared__ int lh[256];
    lh[threadIdx.x] = 0;
    __syncthreads();
    for (int v = blockIdx.x * blockDim.x + threadIdx.x; v < n; v += gridDim.x * blockDim.x)
        atomicAdd(&lh[min(degi[v], 255)], 1);
    __syncthreads();
    int c = lh[threadIdx.x];
    if (c) atomicAdd(&dh[threadIdx.x], c);
}

__global__ void dscan_kernel(const int* __restrict__ dh, int* __restrict__ dcur) {
    __shared__ int s[256];
    int t = threadIdx.x;
    int mine = dh[t];
    s[t] = mine;
    __syncthreads();
    for (int off = 1; off < 256; off <<= 1) {
        int val = (t >= off) ? s[t - off] : 0;
        __syncthreads();
        s[t] += val;
        __syncthreads();
    }
    dcur[t] = s[t] - mine;  // exclusive
}

// ---- placement: per-block chunk, LDS hist -> bulk range reservation -> LDS rank ----
__global__ void place_kernel(const int* __restrict__ degi, int* __restrict__ dcur,
                             int* __restrict__ perm, int n) {
    __shared__ int lh[256], lb[256];
    int chunk = (n + gridDim.x - 1) / gridDim.x;
    int beg = blockIdx.x * chunk;
    int end = min(beg + chunk, n);
    lh[threadIdx.x] = 0;
    __syncthreads();
    for (int v = beg + threadIdx.x; v < end; v += blockDim.x)
        atomicAdd(&lh[min(degi[v], 255)], 1);
    __syncthreads();
    int c = lh[threadIdx.x];
    lb[threadIdx.x] = c ? atomicAdd(&dcur[threadIdx.x], c) : 0;
    __syncthreads();
    lh[threadIdx.x] = 0;
    __syncthreads();
    for (int v = beg + threadIdx.x; v < end; v += blockDim.x) {
        int bin = min(degi[v], 255);
        int r = atomicAdd(&lh[bin], 1);
        perm[lb[bin] + r] = v;
    }
}

// ---- x0s = bf16(dinv[v] * x) ----
__global__ void cvt_kernel(const float* __restrict__ x, const float* __restrict__ dinv,
                           unsigned short* __restrict__ xb, int n4) {
    int i = blockIdx.x * blockDim.x + threadIdx.x;
    if (i < n4) {
        float dv = dinv[i >> 4];
        float4 f = ((const float4*)x)[i];
        bf16 b0 = __float2bfloat16(f.x * dv), b1 = __float2bfloat16(f.y * dv);
        bf16 b2 = __float2bfloat16(f.z * dv), b3 = __float2bfloat16(f.w * dv);
        ushort4 u;
        u.x = *(unsigned short*)&b0; u.y = *(unsigned short*)&b1;
        u.z = *(unsigned short*)&b2; u.w = *(unsigned short*)&b3;
        ((ushort4*)xb)[i] = u;
    }
}

// ---- stage W^T into LDS at row stride WROW: Wsm[j*WROW + k] = W[k*64 + j] ----
__device__ __forceinline__ void stage_w(const float* __restrict__ W, float* __restrict__ Wsm) {
    for (int i = threadIdx.x; i < 4096; i += TPB)
        Wsm[(i & 63) * WROW + (i >> 6)] = W[i];
}

// o[lane] = sum_k t[k] * W[k][lane]; immediate-offset LDS reads.
__device__ __forceinline__ float mm64(const float* __restrict__ Wsm, const float* __restrict__ t,
                                      int lane) {
    const float* wrow = &Wsm[lane * WROW];
    float o = 0.0f;
#pragma unroll
    for (int k4 = 0; k4 < 16; ++k4) {
        float4 tt = *(const float4*)(t + k4 * 4);          // b128 broadcast
        float2 wa = *(const float2*)(wrow + k4 * 4);
        float2 wb = *(const float2*)(wrow + k4 * 4 + 2);
        o = fmaf(tt.x, wa.x, o);
        o = fmaf(tt.y, wa.y, o);
        o = fmaf(tt.z, wb.x, o);
        o = fmaf(tt.w, wb.y, o);
    }
    return o;
}

// ---- 4-slot gather: lane = (slot s = lane>>4, feature-quad g = lane&15) ----
struct GRes { float a0, a1, a2, a3; };
__device__ __forceinline__ GRes gather4(const int* __restrict__ srcids, int beg, int deg, int md,
                                        const unsigned short* __restrict__ rowoff) {
    GRes r{0.0f, 0.0f, 0.0f, 0.0f};
    for (int i = 0; i < md; i += 2) {
        int i0 = (i < deg) ? i : 0;
        int i1 = (i + 1 < deg) ? (i + 1) : 0;
        int src0 = srcids[beg + i0];
        int src1 = srcids[beg + i1];
        int2 q0 = *(const int2*)(rowoff + ((size_t)(unsigned)src0 << 6));
        int2 q1 = *(const int2*)(rowoff + ((size_t)(unsigned)src1 << 6));
        float m0 = (i < deg) ? 1.0f : 0.0f;
        float m1 = (i + 1 < deg) ? 1.0f : 0.0f;
        r.a0 = fmaf(m0, lo16(q0.x), r.a0);
        r.a1 = fmaf(m0, hi16(q0.x), r.a1);
        r.a2 = fmaf(m0, lo16(q0.y), r.a2);
        r.a3 = fmaf(m0, hi16(q0.y), r.a3);
        r.a0 = fmaf(m1, lo16(q1.x), r.a0);
        r.a1 = fmaf(m1, hi16(q1.x), r.a1);
        r.a2 = fmaf(m1, lo16(q1.y), r.a2);
        r.a3 = fmaf(m1, hi16(q1.y), r.a3);
    }
    return r;
}

// ---- fused GCN2Conv layer: ys_out = dinv * relu( t @ W ),
//      t = 0.9*dinv*(S + xs_self) + 0.1*sdeg*xs_self ----
__global__ __launch_bounds__(256) void layer_kernel(
        const int* __restrict__ rowptr, const int* __restrict__ degi,
        const int* __restrict__ srcids, const int* __restrict__ perm,
        const unsigned short* __restrict__ xsb, const float* __restrict__ dinv,
        const float* __restrict__ sdeg, const float* __restrict__ W,
        unsigned short* __restrict__ yb, int n) {
    __shared__ __align__(16) float st[4][4][64];
    __shared__ __align__(16) float Wsm[64 * WROW];
    int wid = threadIdx.x >> 6;
    int lane = threadIdx.x & 63;
    int s = lane >> 4;
    int g = lane & 15;
    stage_w(W, Wsm);
    __syncthreads();
    int ntile = (n + 15) >> 4;
    for (int tile = blockIdx.x; tile < ntile; tile += gridDim.x) {
        int base = tile * 16 + wid * 4;
        int vb = base + s;
        int vbc = (vb < n) ? vb : n - 1;
        int v = perm[vbc];
        int beg = rowptr[v];
        int deg = degi[v];
        int md = max(deg, __shfl_xor(deg, 16));
        md = max(md, __shfl_xor(md, 32));
        const unsigned short* rowoff = xsb + (g << 2);
        GRes r = gather4(srcids, beg, deg, md, rowoff);
        int2 qs = *(const int2*)(rowoff + ((size_t)(unsigned)v << 6));
        float xs0 = lo16(qs.x), xs1 = hi16(qs.x), xs2 = lo16(qs.y), xs3 = hi16(qs.y);
        float c9 = 0.9f * dinv[v];
        float c1 = 0.1f * sdeg[v];
        float4 t4;
        t4.x = c9 * (r.a0 + xs0) + c1 * xs0;
        t4.y = c9 * (r.a1 + xs1) + c1 * xs1;
        t4.z = c9 * (r.a2 + xs2) + c1 * xs2;
        t4.w = c9 * (r.a3 + xs3) + c1 * xs3;
        *(float4*)&st[wid][s][g * 4] = t4;
        __builtin_amdgcn_wave_barrier();
#pragma unroll
        for (int ss = 0; ss < 4; ++ss) {
            int vb2 = base + ss;
            if (vb2 >= n) break;
            int v2 = perm[vb2];
            float o = fmaxf(mm64(Wsm, st[wid][ss], lane), 0.0f);
            bf16 ob = __float2bfloat16(dinv[v2] * o);
            yb[(size_t)(unsigned)v2 * 64 + lane] = *(unsigned short*)&ob;
        }
        __builtin_amdgcn_wave_barrier();
    }
}

// ---- plain matmul: xws = x3s @ W_gcn (scales cancel exactly) ----
__global__ __launch_bounds__(256) void mm_kernel(
        const unsigned short* __restrict__ xb, const float* __restrict__ W,
        unsigned short* __restrict__ yb, int n) {
    __shared__ __align__(16) float st[4][64];
    __shared__ __align__(16) float Wsm[64 * WROW];
    int wid = threadIdx.x >> 6;
    int lane = threadIdx.x & 63;
    stage_w(W, Wsm);
    __syncthreads();
    int stride = gridDim.x * 4;
    for (int v = blockIdx.x * 4 + wid; v < n; v += stride) {
        const unsigned short* selfp = xb + ((size_t)(unsigned)v << 6);
        st[wid][lane] = __int_as_float(((int)selfp[lane]) << 16);
        __builtin_amdgcn_wave_barrier();
        float o = mm64(Wsm, st[wid], lane);
        __builtin_amdgcn_wave_barrier();
        bf16 ob = __float2bfloat16(o);
        yb[(size_t)(unsigned)v * 64 + lane] = *(unsigned short*)&ob;
    }
}

// ---- final: h = dinv*(S + xws_self) + b_gcn; out1 = h@W1+b1; out2 = h@W2+b2 ----
__global__ __launch_bounds__(256) void heads_kernel(
        const int* __restrict__ rowptr, const int* __restrict__ degi,
        const int* __restrict__ srcids, const int* __restrict__ perm,
        const unsigned short* __restrict__ xwb, const float* __restrict__ dinv,
        const float* __restrict__ bg,
        const float* __restrict__ W1, const float* __restrict__ b1,
        const float* __restrict__ W2, const float* __restrict__ b2,
        float* __restrict__ out, int n) {
    __shared__ __align__(16) float hs[4][4][64];
    __shared__ __align__(16) float whd[448];   // whd[j*64+k], j=0..6
    __shared__ float bs[8];
    int wid = threadIdx.x >> 6;
    int lane = threadIdx.x & 63;
    int s = lane >> 4;
    int g = lane & 15;
    for (int i = threadIdx.x; i < 448; i += TPB) {   // blockDim 256 < 448: loop!
        int j = i >> 6, k = i & 63;
        whd[i] = (j < 4) ? W1[k * 4 + j] : W2[k * 3 + (j - 4)];
    }
    if (threadIdx.x < 7) bs[threadIdx.x] = (threadIdx.x < 4) ? b1[threadIdx.x] : b2[threadIdx.x - 4];
    __syncthreads();
    int j = lane >> 3;
    int k0 = (lane & 7) * 8;
    int ntile = (n + 15) >> 4;
    for (int tile = blockIdx.x; tile < ntile; tile += gridDim.x) {
        int base = tile * 16 + wid * 4;
        int vb = base + s;
        int vbc = (vb < n) ? vb : n - 1;
        int v = perm[vbc];
        int beg = rowptr[v];
        int deg = degi[v];
        int md = max(deg, __shfl_xor(deg, 16));
        md = max(md, __shfl_xor(md, 32));
        const unsigned short* rowoff = xwb + (g << 2);
        GRes r = gather4(srcids, beg, deg, md, rowoff);
        int2 qs = *(const int2*)(rowoff + ((size_t)(unsigned)v << 6));
        float dv = dinv[v];
        float4 bq = *(const float4*)(bg + g * 4);
        float4 h4;
        h4.x = dv * (r.a0 + lo16(qs.x)) + bq.x;
        h4.y = dv * (r.a1 + hi16(qs.x)) + bq.y;
        h4.z = dv * (r.a2 + lo16(qs.y)) + bq.z;
        h4.w = dv * (r.a3 + hi16(qs.y)) + bq.w;
        if (vb < n)
            *(float4*)&out[(size_t)7 * n + (size_t)(unsigned)v * 64 + g * 4] = h4;
        *(float4*)&hs[wid][s][g * 4] = h4;
        __builtin_amdgcn_wave_barrier();
#pragma unroll
        for (int ss = 0; ss < 4; ++ss) {
            int vb2 = base + ss;
            if (vb2 >= n) break;
            int v2 = perm[vb2];
            float part = 0.0f;
            if (j < 7) {
                float4 h0 = *(const float4*)&hs[wid][ss][k0];
                float4 h1 = *(const float4*)&hs[wid][ss][k0 + 4];
                const float4* wq = (const float4*)&whd[j * 64 + k0];
                float4 w0 = wq[0], w1 = wq[1];
                part = h0.x * w0.x + h0.y * w0.y + h0.z * w0.z + h0.w * w0.w
                     + h1.x * w1.x + h1.y * w1.y + h1.z * w1.z + h1.w * w1.w;
            }
            part += __shfl_down(part, 4);
            part += __shfl_down(part, 2);
            part += __shfl_down(part, 1);
            if ((lane & 7) == 0 && j < 7) {
                float sv = bs[j] + part;
                if (j < 4) out[(size_t)v2 * 4 + j] = sv;
                else       out[(size_t)4 * n + (size_t)v2 * 3 + (j - 4)] = sv;
            }
        }
        __builtin_amdgcn_wave_barrier();
    }
}

extern "C" void kernel_launch(void* const* d_in, const int* in_sizes, int n_in,
                              void* d_out, int out_size, void* d_ws, size_t ws_size,
                              hipStream_t stream) {
    const float* x     = (const float*)d_in[0];
    const int*   ei    = (const int*)d_in[1];
    const float* Ws    = (const float*)d_in[2];
    const float* W_gcn = (const float*)d_in[3];
    const float* b_gcn = (const float*)d_in[4];
    const float* W1    = (const float*)d_in[5];
    const float* b1    = (const float*)d_in[6];
    const float* W2    = (const float*)d_in[7];
    const float* b2    = (const float*)d_in[8];
    float* out = (float*)d_out;

    const int N = in_sizes[0] / 64;
    const int E = in_sizes[1] / 2;
    const int NLAYERS = in_sizes[2] / 4096;  // L-1 = 3
    const int B = (N + 127) >> NBSH;         // node buckets of 128

    // ws layout (ints): degi[N] rowptr[N] bh[800] bcur[800] boff[800]
    //                   dh[256] dcur[256] perm[N] srcids[E+64] ebuf[E]
    // (floats): dinv[N] sdeg[N] | (ushort): x0s, bufA, bufB (N*64 each)
    int*   degi   = (int*)d_ws;
    int*   rowptr = degi + N;
    int*   bh     = rowptr + N;
    int*   bcur   = bh + 800;
    int*   boff   = bcur + 800;
    int*   dh     = boff + 800;
    int*   dcur   = dh + 256;
    int*   perm   = dcur + 256;
    int*   srcids = perm + N;
    unsigned int* ebuf = (unsigned int*)(srcids + E + 64);
    float* dinv   = (float*)(ebuf + E);
    float* sdeg   = dinv + N;
    unsigned short* x0s  = (unsigned short*)(sdeg + N);
    unsigned short* bufA = x0s + (size_t)N * 64;
    unsigned short* bufB = bufA + (size_t)N * 64;

    const int WGRID = 4096;

    // ---- CSR build: two-pass bucket sort ----
    hipMemsetAsync(bh, 0, 800 * sizeof(int), stream);
    hipMemsetAsync(dh, 0, 256 * sizeof(int), stream);
    hipMemsetAsync(srcids + E, 0, 64 * sizeof(int), stream);  // gather tail pad
    ebhist_kernel<<<120, TPB, 0, stream>>>(ei + E, bh, E, B);
    bscan_kernel<<<1, 256, 0, stream>>>(bh, bcur, boff, B, E);
    bucket_scatter_kernel<<<120, TPB, 0, stream>>>(ei, bcur, ebuf, E, B);
    bucket_place_kernel<<<B, 128, 0, stream>>>(boff, ebuf, rowptr, degi, dinv, sdeg,
                                               srcids, N);
    // ---- degree-sorted permutation ----
    dhist_kernel<<<64, 256, 0, stream>>>(degi, dh, N);
    dscan_kernel<<<1, 256, 0, stream>>>(dh, dcur);
    place_kernel<<<64, 256, 0, stream>>>(degi, dcur, perm, N);
    cvt_kernel<<<(N * 16 + TPB - 1) / TPB, TPB, 0, stream>>>(x, dinv, x0s, N * 16);

    // ---- GCN2Conv layers ----
    const unsigned short* xcur = x0s;
    unsigned short* ybuf = bufA;
    for (int i = 0; i < NLAYERS; ++i) {
        layer_kernel<<<WGRID, TPB, 0, stream>>>(rowptr, degi, srcids, perm, xcur,
                                                dinv, sdeg, Ws + (size_t)i * 4096, ybuf, N);
        xcur = ybuf;
        ybuf = (ybuf == bufA) ? bufB : bufA;
    }

    // ---- GCNConv + heads ----
    unsigned short* xw = ybuf;
    mm_kernel<<<WGRID, TPB, 0, stream>>>(xcur, W_gcn, xw, N);
    heads_kernel<<<WGRID, TPB, 0, stream>>>(rowptr, degi, srcids, perm, xw, dinv,
                                            b_gcn, W1, b1, W2, b2, out, N);
}

// Round 9
// 406.429 us; speedup vs baseline: 2.8507x; 1.0684x over previous
//
#include <hip/hip_runtime.h>
#include <hip/hip_bf16.h>

// GCNII fused, bf16 pre-scaled activations (xs = dinv*x), src-only CSR built by
// two-pass bucket sort, 4-node-slot gather waves with 8-edge-deep load pipelining,
// degree-sorted node permutation. N=100000, E=1000000, F=64.
// Output: concat(out1 [N*4], out2 [N*3], h [N*64]) fp32.
// NOTE: record packing (dst&127)<<17 | src requires N <= 131072.

#define TPB 256
#define WROW 66   // W^T row stride in floats (8B-aligned, bank-rotated)
#define NBSH 7    // 128 nodes per bucket
typedef __hip_bfloat16 bf16;

__device__ __forceinline__ float lo16(int u) { return __int_as_float(u << 16); }
__device__ __forceinline__ float hi16(int u) { return __int_as_float(u & 0xffff0000); }

// ---- pass 0: bucket histogram (LDS-privatized) ----
__global__ void ebhist_kernel(const int* __restrict__ col, int* __restrict__ bh,
                              int E, int B) {
    __shared__ int lh[800];
    for (int i = threadIdx.x; i < B; i += blockDim.x) lh[i] = 0;
    __syncthreads();
    for (int e = blockIdx.x * blockDim.x + threadIdx.x; e < E; e += gridDim.x * blockDim.x)
        atomicAdd(&lh[col[e] >> NBSH], 1);
    __syncthreads();
    for (int i = threadIdx.x; i < B; i += blockDim.x) {
        int c = lh[i];
        if (c) atomicAdd(&bh[i], c);
    }
}

// ---- exclusive scan of bh -> bcur (cursors) and boff (bounds, boff[B]=E) ----
__global__ void bscan_kernel(const int* __restrict__ bh, int* __restrict__ bcur,
                             int* __restrict__ boff, int B, int E) {
    __shared__ int s[256];
    int t = threadIdx.x;
    int v[4]; int sum = 0;
#pragma unroll
    for (int i = 0; i < 4; ++i) {
        int idx = t * 4 + i;
        v[i] = (idx < B) ? bh[idx] : 0;
        sum += v[i];
    }
    s[t] = sum;
    __syncthreads();
    for (int off = 1; off < 256; off <<= 1) {
        int val = (t >= off) ? s[t - off] : 0;
        __syncthreads();
        s[t] += val;
        __syncthreads();
    }
    int run = s[t] - sum;
#pragma unroll
    for (int i = 0; i < 4; ++i) {
        int idx = t * 4 + i;
        if (idx < B) { bcur[idx] = run; boff[idx] = run; }
        run += v[i];
    }
    if (t == 255) boff[B] = E;
}

// ---- pass 1: bucket scatter with per-block range reservation ----
__global__ void bucket_scatter_kernel(const int* __restrict__ ei, int* __restrict__ bcur,
                                      unsigned int* __restrict__ ebuf, int E, int B) {
    __shared__ int lh[800], lb[800];
    int chunk = (E + gridDim.x - 1) / gridDim.x;
    int beg = blockIdx.x * chunk;
    int end = min(beg + chunk, E);
    for (int i = threadIdx.x; i < B; i += blockDim.x) lh[i] = 0;
    __syncthreads();
    for (int e = beg + threadIdx.x; e < end; e += blockDim.x)
        atomicAdd(&lh[ei[E + e] >> NBSH], 1);
    __syncthreads();
    for (int i = threadIdx.x; i < B; i += blockDim.x) {
        int c = lh[i];
        lb[i] = c ? atomicAdd(&bcur[i], c) : 0;   // one global atomic per bin per block
    }
    __syncthreads();
    for (int i = threadIdx.x; i < B; i += blockDim.x) lh[i] = 0;
    __syncthreads();
    for (int e = beg + threadIdx.x; e < end; e += blockDim.x) {
        int r = ei[e];
        int c = ei[E + e];
        int bin = c >> NBSH;
        int rank = atomicAdd(&lh[bin], 1);        // LDS rank
        ebuf[lb[bin] + rank] = ((unsigned)(c & 127) << 17) | (unsigned)r;
    }
}

// ---- pass 2: per-bucket place; also emits degi/rowptr/dinv/sdeg ----
__global__ __launch_bounds__(128) void bucket_place_kernel(
        const int* __restrict__ boff, const unsigned int* __restrict__ ebuf,
        int* __restrict__ rowptr, int* __restrict__ degi,
        float* __restrict__ dinv, float* __restrict__ sdeg,
        int* __restrict__ srcids, int n) {
    __shared__ int cnt[128], loff[128], lcur[128];
    int b = blockIdx.x;
    int t = threadIdx.x;
    int lo = boff[b];
    int hi = boff[b + 1];
    int vbase = b << NBSH;
    cnt[t] = 0;
    __syncthreads();
    for (int i = lo + t; i < hi; i += 128)
        atomicAdd(&cnt[ebuf[i] >> 17], 1);
    __syncthreads();
    int mine = cnt[t];
    loff[t] = mine;
    __syncthreads();
    for (int off = 1; off < 128; off <<= 1) {
        int val = (t >= off) ? loff[t - off] : 0;
        __syncthreads();
        loff[t] += val;
        __syncthreads();
    }
    int excl = loff[t] - mine;
    int v = vbase + t;
    if (v < n) {
        rowptr[v] = lo + excl;
        degi[v] = mine;
        float d = (float)mine + 1.0f;
        dinv[v] = rsqrtf(d);
        sdeg[v] = sqrtf(d);
    }
    lcur[t] = lo + excl;
    __syncthreads();
    for (int i = lo + t; i < hi; i += 128) {
        unsigned int r = ebuf[i];
        int pos = atomicAdd(&lcur[r >> 17], 1);
        srcids[pos] = (int)(r & 0x1FFFFu);
    }
}

// ---- degree histogram (LDS-privatized) ----
__global__ void dhist_kernel(const int* __restrict__ degi, int* __restrict__ dh, int n) {
    __shared__ int lh[256];
    lh[threadIdx.x] = 0;
    __syncthreads();
    for (int v = blockIdx.x * blockDim.x + threadIdx.x; v < n; v += gridDim.x * blockDim.x)
        atomicAdd(&lh[min(degi[v], 255)], 1);
    __syncthreads();
    int c = lh[threadIdx.x];
    if (c) atomicAdd(&dh[threadIdx.x], c);
}

__global__ void dscan_kernel(const int* __restrict__ dh, int* __restrict__ dcur) {
    __shared__ int s[256];
    int t = threadIdx.x;
    int mine = dh[t];
    s[t] = mine;
    __syncthreads();
    for (int off = 1; off < 256; off <<= 1) {
        int val = (t >= off) ? s[t - off] : 0;
        __syncthreads();
        s[t] += val;
        __syncthreads();
    }
    dcur[t] = s[t] - mine;  // exclusive
}

// ---- placement: per-block chunk, LDS hist -> bulk range reservation -> LDS rank ----
__global__ void place_kernel(const int* __restrict__ degi, int* __restrict__ dcur,
                             int* __restrict__ perm, int n) {
    __shared__ int lh[256], lb[256];
    int chunk = (n + gridDim.x - 1) / gridDim.x;
    int beg = blockIdx.x * chunk;
    int end = min(beg + chunk, n);
    lh[threadIdx.x] = 0;
    __syncthreads();
    for (int v = beg + threadIdx.x; v < end; v += blockDim.x)
        atomicAdd(&lh[min(degi[v], 255)], 1);
    __syncthreads();
    int c = lh[threadIdx.x];
    lb[threadIdx.x] = c ? atomicAdd(&dcur[threadIdx.x], c) : 0;
    __syncthreads();
    lh[threadIdx.x] = 0;
    __syncthreads();
    for (int v = beg + threadIdx.x; v < end; v += blockDim.x) {
        int bin = min(degi[v], 255);
        int r = atomicAdd(&lh[bin], 1);
        perm[lb[bin] + r] = v;
    }
}

// ---- x0s = bf16(dinv[v] * x) ----
__global__ void cvt_kernel(const float* __restrict__ x, const float* __restrict__ dinv,
                           unsigned short* __restrict__ xb, int n4) {
    int i = blockIdx.x * blockDim.x + threadIdx.x;
    if (i < n4) {
        float dv = dinv[i >> 4];
        float4 f = ((const float4*)x)[i];
        bf16 b0 = __float2bfloat16(f.x * dv), b1 = __float2bfloat16(f.y * dv);
        bf16 b2 = __float2bfloat16(f.z * dv), b3 = __float2bfloat16(f.w * dv);
        ushort4 u;
        u.x = *(unsigned short*)&b0; u.y = *(unsigned short*)&b1;
        u.z = *(unsigned short*)&b2; u.w = *(unsigned short*)&b3;
        ((ushort4*)xb)[i] = u;
    }
}

// ---- stage W^T into LDS at row stride WROW: Wsm[j*WROW + k] = W[k*64 + j] ----
__device__ __forceinline__ void stage_w(const float* __restrict__ W, float* __restrict__ Wsm) {
    for (int i = threadIdx.x; i < 4096; i += TPB)
        Wsm[(i & 63) * WROW + (i >> 6)] = W[i];
}

// o[lane] = sum_k t[k] * W[k][lane]; immediate-offset LDS reads.
__device__ __forceinline__ float mm64(const float* __restrict__ Wsm, const float* __restrict__ t,
                                      int lane) {
    const float* wrow = &Wsm[lane * WROW];
    float o = 0.0f;
#pragma unroll
    for (int k4 = 0; k4 < 16; ++k4) {
        float4 tt = *(const float4*)(t + k4 * 4);          // b128 broadcast
        float2 wa = *(const float2*)(wrow + k4 * 4);
        float2 wb = *(const float2*)(wrow + k4 * 4 + 2);
        o = fmaf(tt.x, wa.x, o);
        o = fmaf(tt.y, wa.y, o);
        o = fmaf(tt.z, wb.x, o);
        o = fmaf(tt.w, wb.y, o);
    }
    return o;
}

// ---- 4-slot gather, 8-edge-deep pipeline: lane = (slot = lane>>4, quad g = lane&15).
// All 8 srcid loads then all 8 row loads issued before the fma tree -> 8 fetches
// in flight per lane (round-8 version only kept 2 -> latency-bound).
struct GRes { float a0, a1, a2, a3; };
__device__ __forceinline__ GRes gather8s(const int* __restrict__ srcids, int beg, int deg,
                                         int md, const unsigned short* __restrict__ rowoff) {
    GRes r{0.0f, 0.0f, 0.0f, 0.0f};
    for (int i = 0; i < md; i += 8) {
        int src[8];
#pragma unroll
        for (int u = 0; u < 8; ++u) {
            int e = i + u;
            src[u] = srcids[beg + ((e < deg) ? e : 0)];
        }
        int2 q[8];
#pragma unroll
        for (int u = 0; u < 8; ++u)
            q[u] = *(const int2*)(rowoff + ((size_t)(unsigned)src[u] << 6));
#pragma unroll
        for (int u = 0; u < 8; ++u) {
            float m = (i + u < deg) ? 1.0f : 0.0f;
            r.a0 = fmaf(m, lo16(q[u].x), r.a0);
            r.a1 = fmaf(m, hi16(q[u].x), r.a1);
            r.a2 = fmaf(m, lo16(q[u].y), r.a2);
            r.a3 = fmaf(m, hi16(q[u].y), r.a3);
        }
    }
    return r;
}

// ---- fused GCN2Conv layer: ys_out = dinv * relu( t @ W ),
//      t = 0.9*dinv*(S + xs_self) + 0.1*sdeg*xs_self ----
__global__ __launch_bounds__(256) void layer_kernel(
        const int* __restrict__ rowptr, const int* __restrict__ degi,
        const int* __restrict__ srcids, const int* __restrict__ perm,
        const unsigned short* __restrict__ xsb, const float* __restrict__ dinv,
        const float* __restrict__ sdeg, const float* __restrict__ W,
        unsigned short* __restrict__ yb, int n) {
    __shared__ __align__(16) float st[4][4][64];
    __shared__ __align__(16) float Wsm[64 * WROW];
    int wid = threadIdx.x >> 6;
    int lane = threadIdx.x & 63;
    int s = lane >> 4;
    int g = lane & 15;
    stage_w(W, Wsm);
    __syncthreads();
    int ntile = (n + 15) >> 4;
    // reversed: high-degree tiles (end of perm) start first -> no heavy tail
    for (int tile = ntile - 1 - blockIdx.x; tile >= 0; tile -= gridDim.x) {
        int base = tile * 16 + wid * 4;
        int vb = base + s;
        int vbc = (vb < n) ? vb : n - 1;
        int v = perm[vbc];
        int beg = rowptr[v];
        int deg = degi[v];
        int md = max(deg, __shfl_xor(deg, 16));
        md = max(md, __shfl_xor(md, 32));
        const unsigned short* rowoff = xsb + (g << 2);
        GRes r = gather8s(srcids, beg, deg, md, rowoff);
        int2 qs = *(const int2*)(rowoff + ((size_t)(unsigned)v << 6));
        float xs0 = lo16(qs.x), xs1 = hi16(qs.x), xs2 = lo16(qs.y), xs3 = hi16(qs.y);
        float c9 = 0.9f * dinv[v];
        float c1 = 0.1f * sdeg[v];
        float4 t4;
        t4.x = c9 * (r.a0 + xs0) + c1 * xs0;
        t4.y = c9 * (r.a1 + xs1) + c1 * xs1;
        t4.z = c9 * (r.a2 + xs2) + c1 * xs2;
        t4.w = c9 * (r.a3 + xs3) + c1 * xs3;
        *(float4*)&st[wid][s][g * 4] = t4;
        __builtin_amdgcn_wave_barrier();
#pragma unroll
        for (int ss = 0; ss < 4; ++ss) {
            int vb2 = base + ss;
            if (vb2 >= n) break;
            int v2 = perm[vb2];
            float o = fmaxf(mm64(Wsm, st[wid][ss], lane), 0.0f);
            bf16 ob = __float2bfloat16(dinv[v2] * o);
            yb[(size_t)(unsigned)v2 * 64 + lane] = *(unsigned short*)&ob;
        }
        __builtin_amdgcn_wave_barrier();
    }
}

// ---- plain matmul: xws = x3s @ W_gcn (scales cancel exactly) ----
__global__ __launch_bounds__(256) void mm_kernel(
        const unsigned short* __restrict__ xb, const float* __restrict__ W,
        unsigned short* __restrict__ yb, int n) {
    __shared__ __align__(16) float st[4][64];
    __shared__ __align__(16) float Wsm[64 * WROW];
    int wid = threadIdx.x >> 6;
    int lane = threadIdx.x & 63;
    stage_w(W, Wsm);
    __syncthreads();
    int stride = gridDim.x * 4;
    for (int v = blockIdx.x * 4 + wid; v < n; v += stride) {
        const unsigned short* selfp = xb + ((size_t)(unsigned)v << 6);
        st[wid][lane] = __int_as_float(((int)selfp[lane]) << 16);
        __builtin_amdgcn_wave_barrier();
        float o = mm64(Wsm, st[wid], lane);
        __builtin_amdgcn_wave_barrier();
        bf16 ob = __float2bfloat16(o);
        yb[(size_t)(unsigned)v * 64 + lane] = *(unsigned short*)&ob;
    }
}

// ---- final: h = dinv*(S + xws_self) + b_gcn; out1 = h@W1+b1; out2 = h@W2+b2 ----
__global__ __launch_bounds__(256) void heads_kernel(
        const int* __restrict__ rowptr, const int* __restrict__ degi,
        const int* __restrict__ srcids, const int* __restrict__ perm,
        const unsigned short* __restrict__ xwb, const float* __restrict__ dinv,
        const float* __restrict__ bg,
        const float* __restrict__ W1, const float* __restrict__ b1,
        const float* __restrict__ W2, const float* __restrict__ b2,
        float* __restrict__ out, int n) {
    __shared__ __align__(16) float hs[4][4][64];
    __shared__ __align__(16) float whd[448];   // whd[j*64+k], j=0..6
    __shared__ float bs[8];
    int wid = threadIdx.x >> 6;
    int lane = threadIdx.x & 63;
    int s = lane >> 4;
    int g = lane & 15;
    for (int i = threadIdx.x; i < 448; i += TPB) {   // blockDim 256 < 448: loop!
        int j = i >> 6, k = i & 63;
        whd[i] = (j < 4) ? W1[k * 4 + j] : W2[k * 3 + (j - 4)];
    }
    if (threadIdx.x < 7) bs[threadIdx.x] = (threadIdx.x < 4) ? b1[threadIdx.x] : b2[threadIdx.x - 4];
    __syncthreads();
    int j = lane >> 3;
    int k0 = (lane & 7) * 8;
    int ntile = (n + 15) >> 4;
    for (int tile = ntile - 1 - blockIdx.x; tile >= 0; tile -= gridDim.x) {
        int base = tile * 16 + wid * 4;
        int vb = base + s;
        int vbc = (vb < n) ? vb : n - 1;
        int v = perm[vbc];
        int beg = rowptr[v];
        int deg = degi[v];
        int md = max(deg, __shfl_xor(deg, 16));
        md = max(md, __shfl_xor(md, 32));
        const unsigned short* rowoff = xwb + (g << 2);
        GRes r = gather8s(srcids, beg, deg, md, rowoff);
        int2 qs = *(const int2*)(rowoff + ((size_t)(unsigned)v << 6));
        float dv = dinv[v];
        float4 bq = *(const float4*)(bg + g * 4);
        float4 h4;
        h4.x = dv * (r.a0 + lo16(qs.x)) + bq.x;
        h4.y = dv * (r.a1 + hi16(qs.x)) + bq.y;
        h4.z = dv * (r.a2 + lo16(qs.y)) + bq.z;
        h4.w = dv * (r.a3 + hi16(qs.y)) + bq.w;
        if (vb < n)
            *(float4*)&out[(size_t)7 * n + (size_t)(unsigned)v * 64 + g * 4] = h4;
        *(float4*)&hs[wid][s][g * 4] = h4;
        __builtin_amdgcn_wave_barrier();
#pragma unroll
        for (int ss = 0; ss < 4; ++ss) {
            int vb2 = base + ss;
            if (vb2 >= n) break;
            int v2 = perm[vb2];
            float part = 0.0f;
            if (j < 7) {
                float4 h0 = *(const float4*)&hs[wid][ss][k0];
                float4 h1 = *(const float4*)&hs[wid][ss][k0 + 4];
                const float4* wq = (const float4*)&whd[j * 64 + k0];
                float4 w0 = wq[0], w1 = wq[1];
                part = h0.x * w0.x + h0.y * w0.y + h0.z * w0.z + h0.w * w0.w
                     + h1.x * w1.x + h1.y * w1.y + h1.z * w1.z + h1.w * w1.w;
            }
            part += __shfl_down(part, 4);
            part += __shfl_down(part, 2);
            part += __shfl_down(part, 1);
            if ((lane & 7) == 0 && j < 7) {
                float sv = bs[j] + part;
                if (j < 4) out[(size_t)v2 * 4 + j] = sv;
                else       out[(size_t)4 * n + (size_t)v2 * 3 + (j - 4)] = sv;
            }
        }
        __builtin_amdgcn_wave_barrier();
    }
}

extern "C" void kernel_launch(void* const* d_in, const int* in_sizes, int n_in,
                              void* d_out, int out_size, void* d_ws, size_t ws_size,
                              hipStream_t stream) {
    const float* x     = (const float*)d_in[0];
    const int*   ei    = (const int*)d_in[1];
    const float* Ws    = (const float*)d_in[2];
    const float* W_gcn = (const float*)d_in[3];
    const float* b_gcn = (const float*)d_in[4];
    const float* W1    = (const float*)d_in[5];
    const float* b1    = (const float*)d_in[6];
    const float* W2    = (const float*)d_in[7];
    const float* b2    = (const float*)d_in[8];
    float* out = (float*)d_out;

    const int N = in_sizes[0] / 64;
    const int E = in_sizes[1] / 2;
    const int NLAYERS = in_sizes[2] / 4096;  // L-1 = 3
    const int B = (N + 127) >> NBSH;         // node buckets of 128

    // ws layout (ints): degi[N] rowptr[N] bh[800] bcur[800] boff[800]
    //                   dh[256] dcur[256] perm[N] srcids[E+64] ebuf[E]
    // (floats): dinv[N] sdeg[N] | (ushort): x0s, bufA, bufB (N*64 each)
    int*   degi   = (int*)d_ws;
    int*   rowptr = degi + N;
    int*   bh     = rowptr + N;
    int*   bcur   = bh + 800;
    int*   boff   = bcur + 800;
    int*   dh     = boff + 800;
    int*   dcur   = dh + 256;
    int*   perm   = dcur + 256;
    int*   srcids = perm + N;
    unsigned int* ebuf = (unsigned int*)(srcids + E + 64);
    float* dinv   = (float*)(ebuf + E);
    float* sdeg   = dinv + N;
    unsigned short* x0s  = (unsigned short*)(sdeg + N);
    unsigned short* bufA = x0s + (size_t)N * 64;
    unsigned short* bufB = bufA + (size_t)N * 64;

    const int WGRID = 4096;

    // ---- CSR build: two-pass bucket sort ----
    hipMemsetAsync(bh, 0, 800 * sizeof(int), stream);
    hipMemsetAsync(dh, 0, 256 * sizeof(int), stream);
    hipMemsetAsync(srcids + E, 0, 64 * sizeof(int), stream);  // gather tail pad
    ebhist_kernel<<<120, TPB, 0, stream>>>(ei + E, bh, E, B);
    bscan_kernel<<<1, 256, 0, stream>>>(bh, bcur, boff, B, E);
    bucket_scatter_kernel<<<120, TPB, 0, stream>>>(ei, bcur, ebuf, E, B);
    bucket_place_kernel<<<B, 128, 0, stream>>>(boff, ebuf, rowptr, degi, dinv, sdeg,
                                               srcids, N);
    // ---- degree-sorted permutation ----
    dhist_kernel<<<64, 256, 0, stream>>>(degi, dh, N);
    dscan_kernel<<<1, 256, 0, stream>>>(dh, dcur);
    place_kernel<<<64, 256, 0, stream>>>(degi, dcur, perm, N);
    cvt_kernel<<<(N * 16 + TPB - 1) / TPB, TPB, 0, stream>>>(x, dinv, x0s, N * 16);

    // ---- GCN2Conv layers ----
    const unsigned short* xcur = x0s;
    unsigned short* ybuf = bufA;
    for (int i = 0; i < NLAYERS; ++i) {
        layer_kernel<<<WGRID, TPB, 0, stream>>>(rowptr, degi, srcids, perm, xcur,
                                                dinv, sdeg, Ws + (size_t)i * 4096, ybuf, N);
        xcur = ybuf;
        ybuf = (ybuf == bufA) ? bufB : bufA;
    }

    // ---- GCNConv + heads ----
    unsigned short* xw = ybuf;
    mm_kernel<<<WGRID, TPB, 0, stream>>>(xcur, W_gcn, xw, N);
    heads_kernel<<<WGRID, TPB, 0, stream>>>(rowptr, degi, srcids, perm, xw, dinv,
                                            b_gcn, W1, b1, W2, b2, out, N);
}